// Round 6
// baseline (393.650 us; speedup 1.0000x reference)
//
#include <hip/hip_runtime.h>
#include <hip/hip_bf16.h>

#define N_PTS (4096 * 192)
#define STRIDE 136     // bf16 elems per LDS act row
#define TM 128         // points per block
#define PB_STRIDE 24   // posb row stride

typedef __bf16 bf16x8 __attribute__((ext_vector_type(8)));
typedef __bf16 bf16x4 __attribute__((ext_vector_type(4)));
typedef float  f32x4  __attribute__((ext_vector_type(4)));
typedef float  f32x2  __attribute__((ext_vector_type(2)));

// ws layout (bf16 element offsets), weight tiles transposed to [n][k]:
#define W1T 0          // 128x128
#define W2T 16384      // 128x128 (rows 0..127 of w2)
#define W3T 32768      // 128x128
#define WFT 49152      // 128x128
#define WRT 65536      // 64x128
#define W0E 73728      // 128x16  fixup: k0-2 w0_hi, k3-5 w0_hi(dup), k6-8 w0_lo
#define W2E 75776      // 128x16  same from w2 rows 128-130
#define WRE 77824      // 64x16   fixup: k9-14 wr vdir rows
#define WDT 78848      // 16x128  (unused this round; kept for layout stability)
#define WSF 80896      // float region: woT[3][64]

__global__ void prep_kernel(const float* __restrict__ w0, const float* __restrict__ w1,
                            const float* __restrict__ w2, const float* __restrict__ w3,
                            const float* __restrict__ wf, const float* __restrict__ wr,
                            const float* __restrict__ wd, const float* __restrict__ wo,
                            __bf16* __restrict__ ws) {
  int i = blockIdx.x * 256 + threadIdx.x;
  if (i < 16384) { int n = i >> 7, k = i & 127; ws[i] = (__bf16)w1[k * 128 + n]; }
  else if (i < 32768) { int j = i - 16384, n = j >> 7, k = j & 127; ws[i] = (__bf16)w2[k * 128 + n]; }
  else if (i < 49152) { int j = i - 32768, n = j >> 7, k = j & 127; ws[i] = (__bf16)w3[k * 128 + n]; }
  else if (i < 65536) { int j = i - 49152, n = j >> 7, k = j & 127; ws[i] = (__bf16)wf[k * 128 + n]; }
  else if (i < 73728) { int j = i - 65536, n = j >> 7, k = j & 127; ws[i] = (__bf16)wr[k * 64 + n]; }
  else if (i < 75776) {
    int j = i - 73728, f = j >> 4, k = j & 15; float v = 0.f;
    if (k < 3)      v = w0[k * 128 + f];
    else if (k < 6) v = w0[(k - 3) * 128 + f];
    else if (k < 9) { float w = w0[(k - 6) * 128 + f]; v = w - (float)(__bf16)w; }
    ws[i] = (__bf16)v;
  }
  else if (i < 77824) {
    int j = i - 75776, f = j >> 4, k = j & 15; float v = 0.f;
    if (k < 3)      v = w2[(128 + k) * 128 + f];
    else if (k < 6) v = w2[(128 + k - 3) * 128 + f];
    else if (k < 9) { float w = w2[(128 + k - 6) * 128 + f]; v = w - (float)(__bf16)w; }
    ws[i] = (__bf16)v;
  }
  else if (i < 78848) {
    int j = i - 77824, n = j >> 4, k = j & 15; float v = 0.f;
    if (k >= 9 && k < 15) v = wr[(128 + ((k - 9) % 3)) * 64 + n];
    ws[i] = (__bf16)v;
  }
  else if (i < 80896) {
    int j = i - 78848, n = j >> 7, k = j & 127; float v = 0.f;
    if (n == 0) v = wd[k];
    ws[i] = (__bf16)v;
  }
  else if (i < 81088) {
    int g = i - 80896, c = g >> 6, kg = g & 63;
    float* wsf = (float*)(ws + WSF);
    wsf[g] = wo[kg * 3 + c];
  }
}

// acc[pt][nt] += wT-tile (A: M=feats) x act-tile (B: N=points), K=128.
template <int PT, int NT>
__device__ __forceinline__ void gemmW(const __bf16* __restrict__ actb,
                                      const __bf16* __restrict__ wT,
                                      f32x4 (&acc)[PT][NT], int l16, int quad) {
#pragma unroll
  for (int kk = 0; kk < 4; ++kk) {
    bf16x8 w[NT];
#pragma unroll
    for (int nt = 0; nt < NT; ++nt)
      w[nt] = *(const bf16x8*)(wT + (size_t)(nt * 16 + l16) * 128 + kk * 32 + quad * 8);
#pragma unroll
    for (int pt = 0; pt < PT; ++pt) {
      bf16x8 a = *(const bf16x8*)(actb + (pt * 16 + l16) * STRIDE + kk * 32 + quad * 8);
#pragma unroll
      for (int nt = 0; nt < NT; ++nt)
        acc[pt][nt] = __builtin_amdgcn_mfma_f32_16x16x32_bf16(w[nt], a, acc[pt][nt], 0, 0, 0);
    }
  }
}

// One K=32 MFMA block vs posb (k0-15 meaningful; quads 2-3 feed zeros).
template <int PT, int NT>
__device__ __forceinline__ void gemmFix(const __bf16* __restrict__ posb,
                                        const __bf16* __restrict__ wext,
                                        f32x4 (&acc)[PT][NT], int l16, int quad) {
  bf16x8 z;
#pragma unroll
  for (int i = 0; i < 8; ++i) z[i] = (__bf16)0.f;
  bf16x8 w[NT];
#pragma unroll
  for (int nt = 0; nt < NT; ++nt) w[nt] = z;
  if (quad < 2) {
#pragma unroll
    for (int nt = 0; nt < NT; ++nt)
      w[nt] = *(const bf16x8*)(wext + (size_t)(nt * 16 + l16) * 16 + quad * 8);
  }
#pragma unroll
  for (int pt = 0; pt < PT; ++pt) {
    bf16x8 b = z;
    if (quad < 2) b = *(const bf16x8*)(posb + (pt * 16 + l16) * PB_STRIDE + quad * 8);
#pragma unroll
    for (int nt = 0; nt < NT; ++nt)
      acc[pt][nt] = __builtin_amdgcn_mfma_f32_16x16x32_bf16(w[nt], b, acc[pt][nt], 0, 0, 0);
  }
}

__device__ __forceinline__ void store_relu(f32x4 v, __bf16* dst) {
  bf16x4 p;
#pragma unroll
  for (int r = 0; r < 4; ++r) p[r] = (__bf16)fmaxf(v[r], 0.f);
  *(bf16x4*)dst = p;
}

template <int PT, int NT>
__device__ __forceinline__ void epilogue(f32x4 (&acc)[PT][NT], __bf16* actp, int l16, int quad) {
#pragma unroll
  for (int nt = 0; nt < NT; ++nt)
#pragma unroll
    for (int pt = 0; pt < PT; ++pt)
      store_relu(acc[pt][nt], actp + (pt * 16 + l16) * STRIDE + nt * 16 + quad * 4);
}

template <int NT>
__device__ __forceinline__ void bias_init(f32x4 (&acc)[4][NT], const float* __restrict__ b,
                                          int featbase, int quad) {
#pragma unroll
  for (int nt = 0; nt < NT; ++nt) {
    f32x4 bv = *(const f32x4*)(b + featbase + nt * 16 + quad * 4);
#pragma unroll
    for (int pt = 0; pt < 4; ++pt) acc[pt][nt] = bv;
  }
}

__global__ __launch_bounds__(256, 4) void nerf_kernel(
    const float* __restrict__ x,
    const float* __restrict__ b0, const float* __restrict__ b1,
    const float* __restrict__ b2, const float* __restrict__ b3,
    const float* __restrict__ wd, const float* __restrict__ bd,
    const float* __restrict__ bfv, const float* __restrict__ br,
    const float* __restrict__ bo,
    const __bf16* __restrict__ ws,
    float* __restrict__ out) {
  __shared__ __bf16 act[TM * STRIDE];        // 34,816 B
  __shared__ __bf16 posb[TM * PB_STRIDE];    //  6,144 B (total 40,960 -> 4 blocks/CU)

  const int tid  = threadIdx.x;
  const int wv   = tid >> 6;
  const int lane = tid & 63;
  const int quad = lane >> 4;
  const int l16  = lane & 15;
  const int p0   = blockIdx.x * TM;
  const int wrow = wv & 1;          // point half
  const int wcol = wv >> 1;         // feature half
  const int ptbase = wrow * 64;
  const int featbase = wcol * 64;

  const __bf16* actA  = act + ptbase * STRIDE;
  const __bf16* posbA = posb + ptbase * PB_STRIDE;
  __bf16* actE = act + ptbase * STRIDE + featbase;

  // ---- stage posb: pos hi/lo + vdir hi/lo ----
  if (tid < TM) {
    const float* xp = x + (size_t)(p0 + tid) * 6;
    f32x2 a = *(const f32x2*)xp;
    f32x2 b = *(const f32x2*)(xp + 2);
    f32x2 c = *(const f32x2*)(xp + 4);
    float px = a[0], py = a[1], pz = b[0], vx = b[1], vy = c[0], vz = c[1];
    __bf16 phx = (__bf16)px, phy = (__bf16)py, phz = (__bf16)pz;
    __bf16 vhx = (__bf16)vx, vhy = (__bf16)vy, vhz = (__bf16)vz;
    __bf16 plx = (__bf16)(px - (float)phx), ply = (__bf16)(py - (float)phy), plz = (__bf16)(pz - (float)phz);
    __bf16 vlx = (__bf16)(vx - (float)vhx), vly = (__bf16)(vy - (float)vhy), vlz = (__bf16)(vz - (float)vhz);
    bf16x8 r0, r1;
    r0[0] = phx; r0[1] = phy; r0[2] = phz; r0[3] = plx; r0[4] = ply; r0[5] = plz; r0[6] = phx; r0[7] = phy;
    r1[0] = phz; r1[1] = vhx; r1[2] = vhy; r1[3] = vhz; r1[4] = vlx; r1[5] = vly; r1[6] = vlz; r1[7] = (__bf16)0.f;
    *(bf16x8*)(posb + tid * PB_STRIDE) = r0;
    *(bf16x8*)(posb + tid * PB_STRIDE + 8) = r1;
  }
  __syncthreads();

  // ---- layer 0 ----
  {
    f32x4 acc[4][4];
    bias_init<4>(acc, b0, featbase, quad);
    gemmFix<4, 4>(posbA, ws + W0E + featbase * 16, acc, l16, quad);
    epilogue<4, 4>(acc, actE, l16, quad);
    __syncthreads();
  }

  // ---- layer 1 ----
  {
    f32x4 acc[4][4];
    bias_init<4>(acc, b1, featbase, quad);
    gemmW<4, 4>(actA, ws + W1T + (size_t)featbase * 128, acc, l16, quad);
    __syncthreads();
    epilogue<4, 4>(acc, actE, l16, quad);
    __syncthreads();
  }

  // ---- layer 2: + pos concat via fixup-MFMA ----
  {
    f32x4 acc[4][4];
    bias_init<4>(acc, b2, featbase, quad);
    gemmW<4, 4>(actA, ws + W2T + (size_t)featbase * 128, acc, l16, quad);
    gemmFix<4, 4>(posbA, ws + W2E + featbase * 16, acc, l16, quad);
    __syncthreads();
    epilogue<4, 4>(acc, actE, l16, quad);
    __syncthreads();
  }

  // ---- layer 3 ----
  {
    f32x4 acc[4][4];
    bias_init<4>(acc, b3, featbase, quad);
    gemmW<4, 4>(actA, ws + W3T + (size_t)featbase * 128, acc, l16, quad);
    __syncthreads();
    epilogue<4, 4>(acc, actE, l16, quad);
    __syncthreads();
  }

  // ---- density = relu(h3 @ wd + bd): proven VALU path (fp32 wd, bf16 h3) ----
  // Reads-only on act; features gemm below also only reads until its barrier.
  {
    int p = tid >> 1, half = tid & 1;
    const __bf16* hrow = act + p * STRIDE + half * 64;
    const float*  wdp  = wd + half * 64;
    float s = 0.f;
#pragma unroll
    for (int c = 0; c < 8; ++c) {
      bf16x8 h = *(const bf16x8*)(hrow + c * 8);
      f32x4 wa = *(const f32x4*)(wdp + c * 8);
      f32x4 wb = *(const f32x4*)(wdp + c * 8 + 4);
      s += (float)h[0] * wa[0] + (float)h[1] * wa[1] + (float)h[2] * wa[2] + (float)h[3] * wa[3];
      s += (float)h[4] * wb[0] + (float)h[5] * wb[1] + (float)h[6] * wb[2] + (float)h[7] * wb[3];
    }
    s += __shfl_xor(s, 1, 64);
    if (half == 0) out[(size_t)3 * N_PTS + p0 + p] = fmaxf(s + bd[0], 0.f);
  }

  // ---- features = relu(h3 @ wf + bf) ----
  {
    f32x4 acc[4][4];
    bias_init<4>(acc, bfv, featbase, quad);
    gemmW<4, 4>(actA, ws + WFT + (size_t)featbase * 128, acc, l16, quad);
    __syncthreads();
    epilogue<4, 4>(acc, actE, l16, quad);
    __syncthreads();
  }

  // ---- r = relu([features, vdir] @ wr + br), 64 outs: wcol owns 32 ----
  {
    f32x4 acc[4][2];
    int fb = wcol * 32;
#pragma unroll
    for (int nt = 0; nt < 2; ++nt) {
      f32x4 bv = *(const f32x4*)(br + fb + nt * 16 + quad * 4);
#pragma unroll
      for (int pt = 0; pt < 4; ++pt) acc[pt][nt] = bv;
    }
    gemmW<4, 2>(actA, ws + WRT + (size_t)fb * 128, acc, l16, quad);
    gemmFix<4, 2>(posbA, ws + WRE + fb * 16, acc, l16, quad);
    __syncthreads();
#pragma unroll
    for (int nt = 0; nt < 2; ++nt)
#pragma unroll
      for (int pt = 0; pt < 4; ++pt)
        store_relu(acc[pt][nt], act + (ptbase + pt * 16 + l16) * STRIDE + fb + nt * 16 + quad * 4);
    __syncthreads();
  }

  // ---- rgb = sigmoid(r @ wo + bo) ----
  {
    const float* woT = (const float*)(ws + WSF);  // [3][64]
    int p = tid >> 1, half = tid & 1;
    const __bf16* rrow = act + p * STRIDE + half * 32;
    float s0 = 0.f, s1 = 0.f, s2 = 0.f;
#pragma unroll
    for (int c = 0; c < 4; ++c) {
      bf16x8 h = *(const bf16x8*)(rrow + c * 8);
#pragma unroll
      for (int j = 0; j < 8; ++j) {
        int kg = half * 32 + c * 8 + j;
        float rv = (float)h[j];
        s0 += rv * woT[kg];
        s1 += rv * woT[64 + kg];
        s2 += rv * woT[128 + kg];
      }
    }
    s0 += __shfl_xor(s0, 1, 64);
    s1 += __shfl_xor(s1, 1, 64);
    s2 += __shfl_xor(s2, 1, 64);
    if (half == 0) {
      size_t o = (size_t)(p0 + p) * 3;
      out[o + 0] = 1.f / (1.f + __expf(-(s0 + bo[0])));
      out[o + 1] = 1.f / (1.f + __expf(-(s1 + bo[1])));
      out[o + 2] = 1.f / (1.f + __expf(-(s2 + bo[2])));
    }
  }
}

extern "C" void kernel_launch(void* const* d_in, const int* in_sizes, int n_in,
                              void* d_out, int out_size, void* d_ws, size_t ws_size,
                              hipStream_t stream) {
  const float* x  = (const float*)d_in[0];
  const float* w0 = (const float*)d_in[1];
  const float* b0 = (const float*)d_in[2];
  const float* w1 = (const float*)d_in[3];
  const float* b1 = (const float*)d_in[4];
  const float* w2 = (const float*)d_in[5];
  const float* b2 = (const float*)d_in[6];
  const float* w3 = (const float*)d_in[7];
  const float* b3 = (const float*)d_in[8];
  const float* wd = (const float*)d_in[9];
  const float* bd = (const float*)d_in[10];
  const float* wf = (const float*)d_in[11];
  const float* bfv= (const float*)d_in[12];
  const float* wr = (const float*)d_in[13];
  const float* br = (const float*)d_in[14];
  const float* wo = (const float*)d_in[15];
  const float* bo = (const float*)d_in[16];
  __bf16* ws = (__bf16*)d_ws;
  float* out = (float*)d_out;

  prep_kernel<<<317, 256, 0, stream>>>(w0, w1, w2, w3, wf, wr, wd, wo, ws);
  nerf_kernel<<<N_PTS / TM, 256, 0, stream>>>(x, b0, b1, b2, b3, wd, bd, bfv, br, bo, ws, out);
}

// Round 7
// 380.049 us; speedup vs baseline: 1.0358x; 1.0358x over previous
//
#include <hip/hip_runtime.h>
#include <hip/hip_bf16.h>

#define N_PTS (4096 * 192)
#define STRIDE 136     // bf16 elems per LDS act row
#define TM 128         // points per block
#define PB_STRIDE 24   // posb row stride

typedef __bf16 bf16x8 __attribute__((ext_vector_type(8)));
typedef __bf16 bf16x4 __attribute__((ext_vector_type(4)));
typedef float  f32x4  __attribute__((ext_vector_type(4)));
typedef float  f32x2  __attribute__((ext_vector_type(2)));

// ws layout (bf16 element offsets), weight tiles transposed to [n][k]:
#define W1T 0          // 128x128
#define W2T 16384      // 128x128 (rows 0..127 of w2)
#define W3T 32768      // 128x128
#define WFT 49152      // 128x128
#define WRT 65536      // 64x128
#define W0E 73728      // 128x16  fixup: k0-2 w0_hi, k3-5 w0_hi(dup), k6-8 w0_lo
#define W2E 75776      // 128x16  same from w2 rows 128-130
#define WRE 77824      // 64x16   fixup: k9-14 wr vdir rows
#define WDT 78848      // 16x128  (unused; layout stability)
#define WSF 80896      // float region: woT[3][64]

__global__ void prep_kernel(const float* __restrict__ w0, const float* __restrict__ w1,
                            const float* __restrict__ w2, const float* __restrict__ w3,
                            const float* __restrict__ wf, const float* __restrict__ wr,
                            const float* __restrict__ wd, const float* __restrict__ wo,
                            __bf16* __restrict__ ws) {
  int i = blockIdx.x * 256 + threadIdx.x;
  if (i < 16384) { int n = i >> 7, k = i & 127; ws[i] = (__bf16)w1[k * 128 + n]; }
  else if (i < 32768) { int j = i - 16384, n = j >> 7, k = j & 127; ws[i] = (__bf16)w2[k * 128 + n]; }
  else if (i < 49152) { int j = i - 32768, n = j >> 7, k = j & 127; ws[i] = (__bf16)w3[k * 128 + n]; }
  else if (i < 65536) { int j = i - 49152, n = j >> 7, k = j & 127; ws[i] = (__bf16)wf[k * 128 + n]; }
  else if (i < 73728) { int j = i - 65536, n = j >> 7, k = j & 127; ws[i] = (__bf16)wr[k * 64 + n]; }
  else if (i < 75776) {
    int j = i - 73728, f = j >> 4, k = j & 15; float v = 0.f;
    if (k < 3)      v = w0[k * 128 + f];
    else if (k < 6) v = w0[(k - 3) * 128 + f];
    else if (k < 9) { float w = w0[(k - 6) * 128 + f]; v = w - (float)(__bf16)w; }
    ws[i] = (__bf16)v;
  }
  else if (i < 77824) {
    int j = i - 75776, f = j >> 4, k = j & 15; float v = 0.f;
    if (k < 3)      v = w2[(128 + k) * 128 + f];
    else if (k < 6) v = w2[(128 + k - 3) * 128 + f];
    else if (k < 9) { float w = w2[(128 + k - 6) * 128 + f]; v = w - (float)(__bf16)w; }
    ws[i] = (__bf16)v;
  }
  else if (i < 78848) {
    int j = i - 77824, n = j >> 4, k = j & 15; float v = 0.f;
    if (k >= 9 && k < 15) v = wr[(128 + ((k - 9) % 3)) * 64 + n];
    ws[i] = (__bf16)v;
  }
  else if (i < 80896) {
    int j = i - 78848, n = j >> 7, k = j & 127; float v = 0.f;
    if (n == 0) v = wd[k];
    ws[i] = (__bf16)v;
  }
  else if (i < 81088) {
    int g = i - 80896, c = g >> 6, kg = g & 63;
    float* wsf = (float*)(ws + WSF);
    wsf[g] = wo[kg * 3 + c];
  }
}

// acc[pt][nt] += wT-tile (A: M=feats) x act-tile (B: N=points), K=128.
// Pressure-shaped: a[PT] preloaded per kk; w-frags processed in pairs.
template <int PT, int NT>
__device__ __forceinline__ void gemmW(const __bf16* __restrict__ actb,
                                      const __bf16* __restrict__ wT,
                                      f32x4 (&acc)[PT][NT], int l16, int quad) {
#pragma unroll
  for (int kk = 0; kk < 4; ++kk) {
    bf16x8 a[PT];
#pragma unroll
    for (int pt = 0; pt < PT; ++pt)
      a[pt] = *(const bf16x8*)(actb + (pt * 16 + l16) * STRIDE + kk * 32 + quad * 8);
#pragma unroll
    for (int nh = 0; nh < NT; nh += 2) {
      bf16x8 w0 = *(const bf16x8*)(wT + (size_t)((nh + 0) * 16 + l16) * 128 + kk * 32 + quad * 8);
      bf16x8 w1 = *(const bf16x8*)(wT + (size_t)((nh + 1) * 16 + l16) * 128 + kk * 32 + quad * 8);
#pragma unroll
      for (int pt = 0; pt < PT; ++pt) {
        acc[pt][nh + 0] = __builtin_amdgcn_mfma_f32_16x16x32_bf16(w0, a[pt], acc[pt][nh + 0], 0, 0, 0);
        acc[pt][nh + 1] = __builtin_amdgcn_mfma_f32_16x16x32_bf16(w1, a[pt], acc[pt][nh + 1], 0, 0, 0);
      }
    }
  }
}

// One K=32 MFMA block vs posb (k0-15 meaningful; quads 2-3 feed zeros).
template <int PT, int NT>
__device__ __forceinline__ void gemmFix(const __bf16* __restrict__ posb,
                                        const __bf16* __restrict__ wext,
                                        f32x4 (&acc)[PT][NT], int l16, int quad) {
  bf16x8 z;
#pragma unroll
  for (int i = 0; i < 8; ++i) z[i] = (__bf16)0.f;
  bf16x8 b[PT];
#pragma unroll
  for (int pt = 0; pt < PT; ++pt) {
    b[pt] = z;
    if (quad < 2) b[pt] = *(const bf16x8*)(posb + (pt * 16 + l16) * PB_STRIDE + quad * 8);
  }
#pragma unroll
  for (int nh = 0; nh < NT; nh += 2) {
    bf16x8 w0 = z, w1 = z;
    if (quad < 2) {
      w0 = *(const bf16x8*)(wext + (size_t)((nh + 0) * 16 + l16) * 16 + quad * 8);
      w1 = *(const bf16x8*)(wext + (size_t)((nh + 1) * 16 + l16) * 16 + quad * 8);
    }
#pragma unroll
    for (int pt = 0; pt < PT; ++pt) {
      acc[pt][nh + 0] = __builtin_amdgcn_mfma_f32_16x16x32_bf16(w0, b[pt], acc[pt][nh + 0], 0, 0, 0);
      acc[pt][nh + 1] = __builtin_amdgcn_mfma_f32_16x16x32_bf16(w1, b[pt], acc[pt][nh + 1], 0, 0, 0);
    }
  }
}

__device__ __forceinline__ void store_relu(f32x4 v, __bf16* dst) {
  bf16x4 p;
#pragma unroll
  for (int r = 0; r < 4; ++r) p[r] = (__bf16)fmaxf(v[r], 0.f);
  *(bf16x4*)dst = p;
}

template <int PT, int NT>
__device__ __forceinline__ void epilogue(f32x4 (&acc)[PT][NT], __bf16* actp, int l16, int quad) {
#pragma unroll
  for (int nt = 0; nt < NT; ++nt)
#pragma unroll
    for (int pt = 0; pt < PT; ++pt)
      store_relu(acc[pt][nt], actp + (pt * 16 + l16) * STRIDE + nt * 16 + quad * 4);
}

template <int NT>
__device__ __forceinline__ void bias_init(f32x4 (&acc)[4][NT], const float* __restrict__ b,
                                          int featbase, int quad) {
#pragma unroll
  for (int nt = 0; nt < NT; ++nt) {
    f32x4 bv = *(const f32x4*)(b + featbase + nt * 16 + quad * 4);
#pragma unroll
    for (int pt = 0; pt < 4; ++pt) acc[pt][nt] = bv;
  }
}

__global__ __launch_bounds__(256, 4) void nerf_kernel(
    const float* __restrict__ x,
    const float* __restrict__ b0, const float* __restrict__ b1,
    const float* __restrict__ b2, const float* __restrict__ b3,
    const float* __restrict__ wd, const float* __restrict__ bd,
    const float* __restrict__ bfv, const float* __restrict__ br,
    const float* __restrict__ bo,
    const __bf16* __restrict__ ws,
    float* __restrict__ out) {
  __shared__ __bf16 act[TM * STRIDE];        // 34,816 B
  __shared__ __bf16 posb[TM * PB_STRIDE];    //  6,144 B (total 40,960 -> 4 blocks/CU)

  const int tid  = threadIdx.x;
  const int wv   = tid >> 6;
  const int lane = tid & 63;
  const int quad = lane >> 4;
  const int l16  = lane & 15;
  const int p0   = blockIdx.x * TM;
  const int wrow = wv & 1;          // point half
  const int wcol = wv >> 1;         // feature half
  const int ptbase = wrow * 64;
  const int featbase = wcol * 64;

  const __bf16* actA  = act + ptbase * STRIDE;
  const __bf16* posbA = posb + ptbase * PB_STRIDE;
  __bf16* actE = act + ptbase * STRIDE + featbase;

  // ---- stage posb: pos hi/lo + vdir hi/lo ----
  if (tid < TM) {
    const float* xp = x + (size_t)(p0 + tid) * 6;
    f32x2 a = *(const f32x2*)xp;
    f32x2 b = *(const f32x2*)(xp + 2);
    f32x2 c = *(const f32x2*)(xp + 4);
    float px = a[0], py = a[1], pz = b[0], vx = b[1], vy = c[0], vz = c[1];
    __bf16 phx = (__bf16)px, phy = (__bf16)py, phz = (__bf16)pz;
    __bf16 vhx = (__bf16)vx, vhy = (__bf16)vy, vhz = (__bf16)vz;
    __bf16 plx = (__bf16)(px - (float)phx), ply = (__bf16)(py - (float)phy), plz = (__bf16)(pz - (float)phz);
    __bf16 vlx = (__bf16)(vx - (float)vhx), vly = (__bf16)(vy - (float)vhy), vlz = (__bf16)(vz - (float)vhz);
    bf16x8 r0, r1;
    r0[0] = phx; r0[1] = phy; r0[2] = phz; r0[3] = plx; r0[4] = ply; r0[5] = plz; r0[6] = phx; r0[7] = phy;
    r1[0] = phz; r1[1] = vhx; r1[2] = vhy; r1[3] = vhz; r1[4] = vlx; r1[5] = vly; r1[6] = vlz; r1[7] = (__bf16)0.f;
    *(bf16x8*)(posb + tid * PB_STRIDE) = r0;
    *(bf16x8*)(posb + tid * PB_STRIDE + 8) = r1;
  }
  __syncthreads();

  // ---- layer 0 ----
  {
    f32x4 acc[4][4];
    bias_init<4>(acc, b0, featbase, quad);
    gemmFix<4, 4>(posbA, ws + W0E + featbase * 16, acc, l16, quad);
    epilogue<4, 4>(acc, actE, l16, quad);
    __syncthreads();
  }

  // ---- layer 1 ----
  {
    f32x4 acc[4][4];
    bias_init<4>(acc, b1, featbase, quad);
    gemmW<4, 4>(actA, ws + W1T + (size_t)featbase * 128, acc, l16, quad);
    __syncthreads();
    epilogue<4, 4>(acc, actE, l16, quad);
    __syncthreads();
  }

  // ---- layer 2: + pos concat via fixup-MFMA ----
  {
    f32x4 acc[4][4];
    bias_init<4>(acc, b2, featbase, quad);
    gemmW<4, 4>(actA, ws + W2T + (size_t)featbase * 128, acc, l16, quad);
    gemmFix<4, 4>(posbA, ws + W2E + featbase * 16, acc, l16, quad);
    __syncthreads();
    epilogue<4, 4>(acc, actE, l16, quad);
    __syncthreads();
  }

  // ---- layer 3 ----
  {
    f32x4 acc[4][4];
    bias_init<4>(acc, b3, featbase, quad);
    gemmW<4, 4>(actA, ws + W3T + (size_t)featbase * 128, acc, l16, quad);
    __syncthreads();
    epilogue<4, 4>(acc, actE, l16, quad);
    __syncthreads();
  }

  // ---- density = relu(h3 @ wd + bd): VALU path, unroll-capped ----
  {
    int p = tid >> 1, half = tid & 1;
    const __bf16* hrow = act + p * STRIDE + half * 64;
    const float*  wdp  = wd + half * 64;
    float s = 0.f;
#pragma unroll 2
    for (int c = 0; c < 8; ++c) {
      bf16x8 h = *(const bf16x8*)(hrow + c * 8);
      f32x4 wa = *(const f32x4*)(wdp + c * 8);
      f32x4 wb = *(const f32x4*)(wdp + c * 8 + 4);
      s += (float)h[0] * wa[0] + (float)h[1] * wa[1] + (float)h[2] * wa[2] + (float)h[3] * wa[3];
      s += (float)h[4] * wb[0] + (float)h[5] * wb[1] + (float)h[6] * wb[2] + (float)h[7] * wb[3];
    }
    s += __shfl_xor(s, 1, 64);
    if (half == 0) out[(size_t)3 * N_PTS + p0 + p] = fmaxf(s + bd[0], 0.f);
  }

  // ---- features = relu(h3 @ wf + bf) ----
  {
    f32x4 acc[4][4];
    bias_init<4>(acc, bfv, featbase, quad);
    gemmW<4, 4>(actA, ws + WFT + (size_t)featbase * 128, acc, l16, quad);
    __syncthreads();
    epilogue<4, 4>(acc, actE, l16, quad);
    __syncthreads();
  }

  // ---- r = relu([features, vdir] @ wr + br), 64 outs: wcol owns 32 ----
  {
    f32x4 acc[4][2];
    int fb = wcol * 32;
#pragma unroll
    for (int nt = 0; nt < 2; ++nt) {
      f32x4 bv = *(const f32x4*)(br + fb + nt * 16 + quad * 4);
#pragma unroll
      for (int pt = 0; pt < 4; ++pt) acc[pt][nt] = bv;
    }
    gemmW<4, 2>(actA, ws + WRT + (size_t)fb * 128, acc, l16, quad);
    gemmFix<4, 2>(posbA, ws + WRE + fb * 16, acc, l16, quad);
    __syncthreads();
#pragma unroll
    for (int nt = 0; nt < 2; ++nt)
#pragma unroll
      for (int pt = 0; pt < 4; ++pt)
        store_relu(acc[pt][nt], act + (ptbase + pt * 16 + l16) * STRIDE + fb + nt * 16 + quad * 4);
    __syncthreads();
  }

  // ---- rgb = sigmoid(r @ wo + bo), unroll-capped ----
  {
    const float* woT = (const float*)(ws + WSF);  // [3][64]
    int p = tid >> 1, half = tid & 1;
    const __bf16* rrow = act + p * STRIDE + half * 32;
    float s0 = 0.f, s1 = 0.f, s2 = 0.f;
#pragma unroll 1
    for (int c = 0; c < 4; ++c) {
      bf16x8 h = *(const bf16x8*)(rrow + c * 8);
#pragma unroll
      for (int j = 0; j < 8; ++j) {
        int kg = half * 32 + c * 8 + j;
        float rv = (float)h[j];
        s0 += rv * woT[kg];
        s1 += rv * woT[64 + kg];
        s2 += rv * woT[128 + kg];
      }
    }
    s0 += __shfl_xor(s0, 1, 64);
    s1 += __shfl_xor(s1, 1, 64);
    s2 += __shfl_xor(s2, 1, 64);
    if (half == 0) {
      size_t o = (size_t)(p0 + p) * 3;
      out[o + 0] = 1.f / (1.f + __expf(-(s0 + bo[0])));
      out[o + 1] = 1.f / (1.f + __expf(-(s1 + bo[1])));
      out[o + 2] = 1.f / (1.f + __expf(-(s2 + bo[2])));
    }
  }
}

extern "C" void kernel_launch(void* const* d_in, const int* in_sizes, int n_in,
                              void* d_out, int out_size, void* d_ws, size_t ws_size,
                              hipStream_t stream) {
  const float* x  = (const float*)d_in[0];
  const float* w0 = (const float*)d_in[1];
  const float* b0 = (const float*)d_in[2];
  const float* w1 = (const float*)d_in[3];
  const float* b1 = (const float*)d_in[4];
  const float* w2 = (const float*)d_in[5];
  const float* b2 = (const float*)d_in[6];
  const float* w3 = (const float*)d_in[7];
  const float* b3 = (const float*)d_in[8];
  const float* wd = (const float*)d_in[9];
  const float* bd = (const float*)d_in[10];
  const float* wf = (const float*)d_in[11];
  const float* bfv= (const float*)d_in[12];
  const float* wr = (const float*)d_in[13];
  const float* br = (const float*)d_in[14];
  const float* wo = (const float*)d_in[15];
  const float* bo = (const float*)d_in[16];
  __bf16* ws = (__bf16*)d_ws;
  float* out = (float*)d_out;

  prep_kernel<<<317, 256, 0, stream>>>(w0, w1, w2, w3, wf, wr, wd, wo, ws);
  nerf_kernel<<<N_PTS / TM, 256, 0, stream>>>(x, b0, b1, b2, b3, wd, bd, bfv, br, bo, ws, out);
}